// Round 5
// baseline (636.653 us; speedup 1.0000x reference)
//
#include <hip/hip_runtime.h>
#include <math.h>

// Problem constants (fixed shapes from setup_inputs):
//   x [4,2048,4096] f32, W [4096,4096] f32, bias [4096] f32,
//   lora_A [16,4096] f32, lora_B [4096,16] f32, out [8192,4096] f32
#define MDIM 8192
#define NDIM 4096
#define KDIM 4096

typedef __attribute__((ext_vector_type(8))) _Float16 h8;
typedef __attribute__((ext_vector_type(4))) _Float16 h4;
typedef __attribute__((ext_vector_type(4))) float f32x4;

typedef const __attribute__((address_space(1))) void* gas_ptr;
typedef __attribute__((address_space(3))) void* las_ptr;

__device__ inline void load16_to_lds(const void* g, void* l) {
  // async global->LDS, 16B/lane; LDS dest = wave-uniform base + lane*16
  __builtin_amdgcn_global_load_lds((gas_ptr)g, (las_ptr)l, 16, 0, 0);
}

// ---------- 4x4 double helpers ----------
__device__ inline void mm4(const double* A, const double* B, double* C) {
#pragma unroll
  for (int p = 0; p < 4; ++p)
#pragma unroll
    for (int q = 0; q < 4; ++q) {
      double s = 0.0;
#pragma unroll
      for (int r = 0; r < 4; ++r) s += A[p * 4 + r] * B[r * 4 + q];
      C[p * 4 + q] = s;
    }
}
__device__ inline void mm4_bt(const double* A, const double* B, double* C) {
  // C = A * B^T
#pragma unroll
  for (int p = 0; p < 4; ++p)
#pragma unroll
    for (int q = 0; q < 4; ++q) {
      double s = 0.0;
#pragma unroll
      for (int r = 0; r < 4; ++r) s += A[p * 4 + r] * B[q * 4 + r];
      C[p * 4 + q] = s;
    }
}

// ---------- kernel 1: Gu/Gv reductions + factored Newton-Schulz ----------
__global__ void ns_kernel(const float* __restrict__ lora_A,
                          const float* __restrict__ lora_B,
                          float* __restrict__ E) {
  const int h = blockIdx.x;
  const int tid = threadIdx.x;
  const int lane = tid & 63;
  const int wave = tid >> 6;

  float gu[16], gv[16];
#pragma unroll
  for (int e = 0; e < 16; ++e) { gu[e] = 0.f; gv[e] = 0.f; }

  for (int o = tid; o < NDIM; o += 256) {
    const float4 bv = *(const float4*)(lora_B + (size_t)o * 16 + h * 4);
    const float bb[4] = {bv.x, bv.y, bv.z, bv.w};
#pragma unroll
    for (int p = 0; p < 4; ++p)
#pragma unroll
      for (int q = 0; q < 4; ++q) gu[p * 4 + q] += bb[p] * bb[q];
  }
  for (int i = tid; i < KDIM; i += 256) {
    float aa[4];
#pragma unroll
    for (int p = 0; p < 4; ++p) aa[p] = lora_A[(size_t)(h * 4 + p) * KDIM + i];
#pragma unroll
    for (int p = 0; p < 4; ++p)
#pragma unroll
      for (int q = 0; q < 4; ++q) gv[p * 4 + q] += aa[p] * aa[q];
  }

#pragma unroll
  for (int e = 0; e < 16; ++e) {
#pragma unroll
    for (int off = 32; off > 0; off >>= 1) {
      gu[e] += __shfl_down(gu[e], off, 64);
      gv[e] += __shfl_down(gv[e], off, 64);
    }
  }
  __shared__ float pu[4][16], pv[4][16];
  if (lane == 0) {
#pragma unroll
    for (int e = 0; e < 16; ++e) { pu[wave][e] = gu[e]; pv[wave][e] = gv[e]; }
  }
  __syncthreads();

  if (tid == 0) {
    double gud[16], gvd[16];
#pragma unroll
    for (int e = 0; e < 16; ++e) {
      gud[e] = (double)pu[0][e] + pu[1][e] + pu[2][e] + pu[3][e];
      gvd[e] = (double)pv[0][e] + pv[1][e] + pv[2][e] + pv[3][e];
    }
    double tr = 0.0;
#pragma unroll
    for (int e = 0; e < 16; ++e) tr += gud[e] * gvd[e];
    const double alpha = sqrt(tr);
    const double n0 = alpha + 1e-7;

    double C[16] = {0};
    C[0] = C[5] = C[10] = C[15] = 1.0 / n0;

    const double a = 3.4445, b = -4.775, c = 2.0315;
    for (int it = 0; it < 5; ++it) {
      double T1[16], D[16], DG[16], DGD[16], GuC[16], F[16], Cn[16];
      mm4(C, gvd, T1);
      mm4_bt(T1, C, D);
      mm4(D, gud, DG);
      mm4(DG, D, DGD);
      mm4(gud, C, GuC);
#pragma unroll
      for (int e = 0; e < 16; ++e) F[e] = b * D[e] + c * DGD[e];
      mm4(F, GuC, Cn);
#pragma unroll
      for (int e = 0; e < 16; ++e) C[e] = a * C[e] + Cn[e];
    }
#pragma unroll
    for (int e = 0; e < 16; ++e) E[h * 16 + e] = (float)(alpha * C[e]);
  }
}

// ---------- kernel 2a: Weff = f16(W + A^T coef), 512 blocks x 16 rows x half-K ----------
__global__ void weff_kernel(const float* __restrict__ W,
                            const float* __restrict__ lora_A,
                            const float* __restrict__ lora_B,
                            const float* __restrict__ E,
                            _Float16* __restrict__ Wh) {
  const int tid = threadIdx.x;
  __shared__ float cf[16][16];                   // [row r][k] combination coeffs
  __shared__ __align__(16) float Asm[16][1024];  // 64KB lora_A chunk
  const int o0 = (blockIdx.x >> 1) * 16;
  const int kh = (blockIdx.x & 1) * 2048;
  {
    const int r = tid >> 4, kk = tid & 15, h = kk >> 2, q = kk & 3;
    float s = 0.f;
#pragma unroll
    for (int p = 0; p < 4; ++p)
      s += lora_B[(size_t)(o0 + r) * 16 + h * 4 + p] * E[h * 16 + p * 4 + q];
    cf[r][kk] = s;
  }
  for (int kb = kh; kb < kh + 2048; kb += 1024) {
    __syncthreads();  // prev chunk's Asm readers done (also publishes cf, iter 0)
#pragma unroll
    for (int j = 0; j < 16; ++j) {
      const int f4 = tid + j * 256;  // 0..4095 float4s, fully coalesced
      const int k = f4 >> 8, c4 = f4 & 255;
      *(float4*)&Asm[k][c4 * 4] =
          *(const float4*)&lora_A[(size_t)k * KDIM + kb + (size_t)c4 * 4];
    }
    __syncthreads();
    float4 av[16];
#pragma unroll
    for (int k = 0; k < 16; ++k) av[k] = *(const float4*)&Asm[k][tid * 4];
#pragma unroll
    for (int r = 0; r < 16; ++r) {
      const size_t base = (size_t)(o0 + r) * KDIM + kb + tid * 4;
      float4 acc = *(const float4*)&W[base];
#pragma unroll
      for (int k = 0; k < 16; ++k) {
        const float cfv = cf[r][k];  // LDS broadcast
        acc.x += cfv * av[k].x; acc.y += cfv * av[k].y;
        acc.z += cfv * av[k].z; acc.w += cfv * av[k].w;
      }
      h4 pk;
      pk[0] = (_Float16)acc.x; pk[1] = (_Float16)acc.y;
      pk[2] = (_Float16)acc.z; pk[3] = (_Float16)acc.w;
      *(h4*)(Wh + base) = pk;
    }
  }
}

// ---------- kernel 2b: cast x f32 -> f16 ----------
__global__ void xcast_kernel(const float* __restrict__ x,
                             _Float16* __restrict__ Xh) {
  const size_t t = (size_t)blockIdx.x * 256 + threadIdx.x;
  const size_t base = t * 8;
  const float4 a = *(const float4*)(x + base);
  const float4 b = *(const float4*)(x + base + 4);
  h8 o;
  o[0] = (_Float16)a.x; o[1] = (_Float16)a.y; o[2] = (_Float16)a.z; o[3] = (_Float16)a.w;
  o[4] = (_Float16)b.x; o[5] = (_Float16)b.y; o[6] = (_Float16)b.z; o[7] = (_Float16)b.w;
  *(h8*)(Xh + base) = o;
}

// ---------- kernel 3: 256x128 GEMM, 4 waves, 2 blocks/CU (co-resident overlap) ----------
// Structural change vs rounds 1-4: the 40% MfmaUtil wall was lockstep 8-wave
// phases (LDS-read bursts and MFMA bursts never overlap on a CU with 1 block).
// Now: 4-wave blocks (2Mx2N, per-wave output stays 128x64 to keep LDS:FLOP ratio),
// BK=32, TRIPLE-buffered LDS = 3*(16K A + 8K B) = 72 KB -> 2 blocks/CU.
// Two co-resident blocks sync independently: one block's read/barrier window
// overlaps the other's MFMA burst on the same SIMDs (m114 mechanism).
// Schedule per K-step t (buffers cycle t%3; stage t+2 into buf[(t+2)%3]):
//   ph0: read a0(4 b128) + b(4); stage A(t+2) lines 0,1;   BAR; 16 MFMA; BAR
//   ph1: read a1(4);             stage A(t+2) L2,3 + B(t+2); BAR; 16 MFMA; vmcnt(6); BAR
// vmcnt(6) at end of ph1 keeps exactly this step's 6 stage-instrs, drains step
// t-1's 6 (issued 2-4 phases earlier) -> buf[(t+1)%3] complete before t+1 reads.
// WAR: stage at t.ph0 targets buf[(t-1)%3], last read finished before t-1.ph1's
// closing barrier. RAW: reads at t.ph0 covered by t-1.ph1's drain+barrier.
// Tail: step 126 ends with vmcnt(0) (drains step-127 stages); step 127 bare.
__launch_bounds__(256, 2)
__global__ void gemm_kernel(const _Float16* __restrict__ Xh,   // [M][K]
                            const _Float16* __restrict__ Wh,   // [N][K]
                            const float* __restrict__ bias,
                            float* __restrict__ out) {         // [M][N]
  __shared__ __align__(16) _Float16 A0s[256 * 32], A1s[256 * 32], A2s[256 * 32];
  __shared__ __align__(16) _Float16 B0s[128 * 32], B1s[128 * 32], B2s[128 * 32];

  const int tid = threadIdx.x;
  const int lane = tid & 63;
  const int wave = tid >> 6;      // 0..3
  const int wm = wave >> 1;       // 0..1: row half (128 rows)
  const int wn = wave & 1;        // 0..1: col half (64 cols)
  const int quad = lane >> 4;     // k-chunk selector
  const int r16 = lane & 15;      // row within 16x16 fragment
  const int swk = (r16 >> 1) & 3; // read-side swizzle key (row>>1)&3 == (r16>>1)&3

  // XCD-aware swizzle: 1024 wgs, 8 XCDs, 128 contiguous wgs per XCD
  // (= 4 bm-panels x all 32 bn: A panels L2-resident per XCD)
  const int lin = blockIdx.x;
  const int wg = (lin & 7) * 128 + (lin >> 3);
  const int bm = wg >> 5;  // 0..31
  const int bn = wg & 31;  // 0..31

  // staging: one line = 64 rows x 64B (4KB = 256 lanes x 16B). thread t:
  // row (t>>2), stored slot (t&3) holds logical chunk (t&3)^((row>>1)&3)
  // (swizzle applied on pre-swizzled global source; LDS dest linear).
  const int srow = tid >> 2;
  const int slc = (tid & 3) ^ ((srow >> 1) & 3);
  const size_t soff = (size_t)srow * KDIM + slc * 8;
  const int ldsb = tid * 16;
  const _Float16* pA = Xh + (size_t)(bm * 256) * KDIM;
  const _Float16* pB = Wh + (size_t)(bn * 128) * KDIM;

  // compute-side LDS element offsets (row*32 + stored_chunk*8)
  const int aBase = (wm * 128 + r16) * 32;
  const int bBase = (wn * 64 + r16) * 32;
  const int c0 = (quad ^ swk) * 8;

  f32x4 acc[2][4][4] = {};
  h8 a0[4], a1[4], bb[4];

#define FENCE() asm volatile("" ::: "memory")
#define BAR() do { FENCE(); __builtin_amdgcn_s_barrier(); FENCE(); } while (0)
#define VMC(n) asm volatile("s_waitcnt vmcnt(" #n ")" ::: "memory")
#define NOPV() do { } while (0)

#define RDA(dst, Ac, F0) do { _Pragma("unroll")                                \
    for (int i = 0; i < 4; ++i)                                                \
      dst[i] = *(const h8*)&Ac[aBase + ((F0) + i) * 512 + c0];                 \
  } while (0)
#define RDB(dst, Bc) do { _Pragma("unroll")                                    \
    for (int g = 0; g < 4; ++g)                                                \
      dst[g] = *(const h8*)&Bc[bBase + g * 512 + c0];                          \
  } while (0)

#define STG_A01(An, kn) do {                                                   \
    load16_to_lds(pA + soff + (kn), (char*)(An) + ldsb);                       \
    load16_to_lds(pA + soff + (size_t)64 * KDIM + (kn),                        \
                  (char*)(An) + 4096 + ldsb);                                  \
  } while (0)
#define STG_A23B(An, Bn, kn) do {                                              \
    load16_to_lds(pA + soff + (size_t)128 * KDIM + (kn),                       \
                  (char*)(An) + 8192 + ldsb);                                  \
    load16_to_lds(pA + soff + (size_t)192 * KDIM + (kn),                       \
                  (char*)(An) + 12288 + ldsb);                                 \
    load16_to_lds(pB + soff + (kn), (char*)(Bn) + ldsb);                       \
    load16_to_lds(pB + soff + (size_t)64 * KDIM + (kn),                        \
                  (char*)(Bn) + 4096 + ldsb);                                  \
  } while (0)

#define MFMA_H(H, AV) do {                                                     \
    __builtin_amdgcn_s_setprio(1);                                             \
    _Pragma("unroll")                                                          \
    for (int i = 0; i < 4; ++i)                                                \
      _Pragma("unroll")                                                        \
      for (int g = 0; g < 4; ++g)                                              \
        acc[H][i][g] = __builtin_amdgcn_mfma_f32_16x16x32_f16(                 \
            AV[i], bb[g], acc[H][i][g], 0, 0, 0);                              \
    __builtin_amdgcn_s_setprio(0);                                             \
  } while (0)

#define STEP(Ac, Bc, An, Bn, kn) do {                                          \
    RDA(a0, Ac, 0); RDB(bb, Bc); STG_A01(An, kn);                              \
    BAR(); MFMA_H(0, a0); BAR();                                               \
    RDA(a1, Ac, 4); STG_A23B(An, Bn, kn);                                      \
    BAR(); MFMA_H(1, a1); VMC(6); BAR();                                       \
  } while (0)

#define STEP_TAIL(Ac, Bc, VEND) do {                                           \
    RDA(a0, Ac, 0); RDB(bb, Bc);                                               \
    BAR(); MFMA_H(0, a0); BAR();                                               \
    RDA(a1, Ac, 4);                                                            \
    BAR(); MFMA_H(1, a1); VEND; BAR();                                         \
  } while (0)

  // prologue: stage steps 0 and 1 in steady-state order; vmcnt(6) keeps exactly
  // step-1's 6 instrs in flight, guarantees step-0 landed.
  STG_A01(A0s, 0);  STG_A23B(A0s, B0s, 0);
  STG_A01(A1s, 32); STG_A23B(A1s, B1s, 32);
  VMC(6);
  BAR();

#pragma unroll 1
  for (int t = 0; t < 126; t += 3) {
    STEP(A0s, B0s, A2s, B2s, (t + 2) * 32);
    STEP(A1s, B1s, A0s, B0s, (t + 3) * 32);
    STEP(A2s, B2s, A1s, B1s, (t + 4) * 32);
  }
  STEP_TAIL(A0s, B0s, VMC(0));  // step 126: drain step-127's stages
  STEP_TAIL(A1s, B1s, NOPV());  // step 127

  // epilogue: D row=(lane>>4)*4+reg (M side), col=lane&15 (N side)
#pragma unroll
  for (int h = 0; h < 2; ++h)
#pragma unroll
    for (int i = 0; i < 4; ++i) {
      float* po = out +
          (size_t)(bm * 256 + wm * 128 + (h * 4 + i) * 16 + quad * 4) * NDIM;
#pragma unroll
      for (int g = 0; g < 4; ++g) {
        const int ocol = bn * 128 + wn * 64 + g * 16 + r16;
        const float bv = bias[ocol];
        const f32x4 v = acc[h][i][g];
#pragma unroll
        for (int rg = 0; rg < 4; ++rg)
          po[(size_t)rg * NDIM + ocol] = v[rg] + bv;
      }
    }
}

extern "C" void kernel_launch(void* const* d_in, const int* in_sizes, int n_in,
                              void* d_out, int out_size, void* d_ws, size_t ws_size,
                              hipStream_t stream) {
  const float* x      = (const float*)d_in[0];  // [8192,4096]
  const float* W      = (const float*)d_in[1];  // [4096,4096]
  const float* bias   = (const float*)d_in[2];  // [4096]
  const float* lora_A = (const float*)d_in[3];  // [16,4096]
  const float* lora_B = (const float*)d_in[4];  // [4096,16]
  float* out = (float*)d_out;

  char* ws = (char*)d_ws;
  float* E = (float*)ws;                                     // 64 floats
  _Float16* Wh = (_Float16*)(ws + 1024);                     // 4096*4096*2 B
  _Float16* Xh = (_Float16*)(ws + 1024 + (size_t)NDIM * KDIM * 2);  // 8192*4096*2 B

  ns_kernel<<<dim3(4), dim3(256), 0, stream>>>(lora_A, lora_B, E);
  xcast_kernel<<<dim3((MDIM * KDIM) / (256 * 8)), dim3(256), 0, stream>>>(x, Xh);
  weff_kernel<<<dim3(512), dim3(256), 0, stream>>>(W, lora_A, lora_B, E, Wh);
  gemm_kernel<<<dim3(1024), dim3(256), 0, stream>>>(Xh, Wh, bias, out);
}